// Round 10
// baseline (159.810 us; speedup 1.0000x reference)
//
#include <hip/hip_runtime.h>
#include <hip/hip_bf16.h>

#define B_  2
#define S_  2048
#define D_  1024
#define H_  16
#define DH_ 64
#define M_  (B_ * S_)       // 4096
#define QKV_LD (3 * D_)     // 3072
#define TOTROWS (B_ * H_ * S_)  // 65536

typedef __bf16 bf16x8 __attribute__((ext_vector_type(8)));
typedef float  f32x4  __attribute__((ext_vector_type(4)));
typedef unsigned short us4 __attribute__((ext_vector_type(4)));
typedef unsigned short us8 __attribute__((ext_vector_type(8)));

__device__ inline unsigned short f2bf(float f) {
  union { __bf16 h; unsigned short u; } cv; cv.h = (__bf16)f; return cv.u;
}
__device__ inline float bf2f(unsigned short u) {
  union { unsigned int i; float f; } cv; cv.i = ((unsigned int)u) << 16; return cv.f;
}
// typed stores: bf16 does the BIT conversion (round-3 bug: (unsigned short)v
// was an int conversion -> output was all-zero)
__device__ inline void cstore(float* p, float v) { *p = v; }
__device__ inline void cstore(unsigned short* p, float v) { *p = f2bf(v); }

__device__ inline void gload_lds16(const void* g, void* lds) {
  __builtin_amdgcn_global_load_lds(
      (const __attribute__((address_space(1))) unsigned int*)g,
      (__attribute__((address_space(3))) unsigned int*)lds, 16, 0, 0);
}

// ---------------- prep: fp32 -> bf16 (row-major copy) ----------------
__global__ __launch_bounds__(256) void conv_bf16(const float* __restrict__ in,
                                                 unsigned short* __restrict__ out, int n4) {
  int i = blockIdx.x * 256 + threadIdx.x;
  if (i >= n4) return;
  float4 v = ((const float4*)in)[i];
  us4 p = { f2bf(v.x), f2bf(v.y), f2bf(v.z), f2bf(v.w) };
  ((us4*)out)[i] = p;
}

// ---------------- prep: fp32 [K][N] -> bf16 [N][K] transpose ----------------
__global__ __launch_bounds__(256) void transpose_bf16(const float* __restrict__ W,
                                                      unsigned short* __restrict__ Wt,
                                                      int K, int N) {
  __shared__ float tile[32][33];
  const int t = threadIdx.x, tx = t & 31, ty = t >> 5;  // ty 0..7
  const int c0 = blockIdx.x * 32, r0 = blockIdx.y * 32;
  #pragma unroll
  for (int i = 0; i < 4; ++i)
    tile[ty + 8 * i][tx] = W[(size_t)(r0 + ty + 8 * i) * N + c0 + tx];
  __syncthreads();
  #pragma unroll
  for (int i = 0; i < 4; ++i)
    Wt[(size_t)(c0 + ty + 8 * i) * K + r0 + tx] = f2bf(tile[tx][ty + 8 * i]);
}

// ---------------- bf16 MFMA GEMM (m97 structure) ----------------
// C[M,N] = A[M,K] @ Bt[N,K]^T + bias.  128x128 tile, BK=32, 4 waves.
template<typename CT>
__global__ __launch_bounds__(256) void gemm_bf16_tn(
    const unsigned short* __restrict__ A,   // [M][K] bf16
    const unsigned short* __restrict__ Bt,  // [N][K] bf16
    const float* __restrict__ bias,
    CT* __restrict__ C, int N, int K) {
  __shared__ __align__(16) unsigned short smA[128 * 32];
  __shared__ __align__(16) unsigned short smB[128 * 32];
  const int t = threadIdx.x;
  const int w = t >> 6, l = t & 63;
  const int lg = l >> 4, lr = l & 15;
  const int row0 = blockIdx.y * 128, col0 = blockIdx.x * 128;
  const int wm = (w >> 1) * 64, wn = (w & 1) * 64;

  f32x4 acc[4][4] = {};

  for (int k0 = 0; k0 < K; k0 += 32) {
    __syncthreads();  // previous iteration's fragment reads complete
    #pragma unroll
    for (int i = 0; i < 2; ++i) {
      const int inst = 2 * w + i;
      const int r = inst * 16 + (l >> 2);
      const int cb = (l & 3) * 8;  // k-chunk of 8 bf16
      gload_lds16(A  + (size_t)(row0 + r) * K + k0 + cb, &smA[inst * 512]);
      gload_lds16(Bt + (size_t)(col0 + r) * K + k0 + cb, &smB[inst * 512]);
    }
    __syncthreads();  // waits vmcnt(0): tiles resident

    bf16x8 af[4], bfr[4];
    #pragma unroll
    for (int m = 0; m < 4; ++m)
      af[m] = *(const bf16x8*)&smA[(wm + m * 16 + lr) * 32 + lg * 8];
    #pragma unroll
    for (int n = 0; n < 4; ++n)
      bfr[n] = *(const bf16x8*)&smB[(wn + n * 16 + lr) * 32 + lg * 8];
    #pragma unroll
    for (int m = 0; m < 4; ++m)
      #pragma unroll
      for (int n = 0; n < 4; ++n)
        acc[m][n] = __builtin_amdgcn_mfma_f32_16x16x32_bf16(af[m], bfr[n], acc[m][n], 0, 0, 0);
  }

  #pragma unroll
  for (int m = 0; m < 4; ++m) {
    #pragma unroll
    for (int n = 0; n < 4; ++n) {
      const int col = col0 + wn + n * 16 + lr;
      const float bv = bias[col];
      #pragma unroll
      for (int r = 0; r < 4; ++r) {
        const int row = row0 + wm + m * 16 + lg * 4 + r;
        cstore(&C[(size_t)row * N + col], acc[m][n][r] + bv);
      }
    }
  }
}

// ---------------- Causal flash attention, bf16 MFMA, split-k x2 ----------------
// 1024 blocks = 8 XCD x 4 bh x 16 balanced q-pairs x 2 k-halves -> 4 blocks/CU.
// Pair x owns q-tiles lo=x and hi=31-x (33 tile-units); the k-range of each
// q-tile is split [0,mid) / [mid,nt) across the two half-blocks (17/16 units,
// same total staging as unsplit). Each half writes normalized partial O (bf16,
// same rounding as final) + (m,l); attn_merge does the LSE combine.
// Round-6 per-wave machinery: 4 waves x 16 q-rows, KVBLK=64, XOR-swizzled LDS,
// dbuf K/V, T14 async staging, 1 barrier/tile.
__global__ __launch_bounds__(256) void attn_fwd_mfma(
    const unsigned short* __restrict__ qkv,
    unsigned short* __restrict__ pO0, unsigned short* __restrict__ pO1,
    float2* __restrict__ pml) {
  const int bid = blockIdx.x + gridDim.x * blockIdx.y;  // 0..1023
  const int xcd = bid & 7;
  const int li  = bid >> 3;             // 0..127 within XCD
  const int bh  = xcd * 4 + (li >> 5);  // 4 bh per XCD
  const int li2 = li & 31;
  const int x   = li2 >> 1;             // balanced q-pair index 0..15
  const int half = li2 & 1;             // k-range half
  const int b = bh / H_, h = bh % H_;
  const unsigned short* base = qkv + (size_t)b * S_ * QKV_LD;

  __shared__ __align__(16) char smK[2][64 * 128];  // K tile [k][d], XOR-swizzled
  __shared__ __align__(16) char smV[2][64 * 128];  // V^T tile [d][k]
  __shared__ __align__(16) char smP[64 * 128];     // P [q][k], wave-private rows

  const int t  = threadIdx.x;
  const int w  = t >> 6;
  const int l  = t & 63;
  const int lg = l >> 4;
  const int lr = l & 15;

  unsigned short* pO = half ? pO1 : pO0;
  float2* pml_h = pml + (size_t)half * TOTROWS;

  const unsigned short* kbase = base + D_ + h * DH_;
  const unsigned short* vbase = base + 2 * D_ + h * DH_;

  // staging registers (T14 async split: issue early, LDS-write late)
  us8 kreg[2], vreg[2];
  const int kp  = (t & 31) * 2;    // V: pair of k-columns
  const int vdb = (t >> 5) * 8;    // V: 8 d-rows

  auto issue_loads = [&](int k0) {
    #pragma unroll
    for (int it = 0; it < 2; ++it) {
      int idx = t + it * 256;
      int r = idx >> 3, c = idx & 7;
      kreg[it] = *(const us8*)(kbase + (size_t)(k0 + r) * QKV_LD + c * 8);
    }
    vreg[0] = *(const us8*)(vbase + (size_t)(k0 + kp) * QKV_LD + vdb);
    vreg[1] = *(const us8*)(vbase + (size_t)(k0 + kp + 1) * QKV_LD + vdb);
  };
  auto write_lds = [&](int buf) {
    #pragma unroll
    for (int it = 0; it < 2; ++it) {
      int idx = t + it * 256;
      int r = idx >> 3, c = idx & 7;
      *(us8*)(smK[buf] + r * 128 + ((c * 16) ^ ((r & 7) << 4))) = kreg[it];
    }
    #pragma unroll
    for (int j = 0; j < 8; ++j) {
      int row = vdb + j;
      unsigned int pv = (unsigned int)vreg[0][j] | ((unsigned int)vreg[1][j] << 16);
      *(unsigned int*)(smV[buf] + row * 128 + ((2 * kp) ^ ((row & 7) << 4))) = pv;
    }
  };

  #pragma unroll 1
  for (int sel = 0; sel < 2; ++sel) {
    const int qt = sel ? (31 - x) : x;
    const int q0 = qt * 64;
    const int qw0 = q0 + w * 16;   // wave owns rows qw0..qw0+15

    const int nt  = qt + 1;            // full k-tile count for this q-tile
    const int mid = (nt + 1) >> 1;     // split point
    const int kb  = half ? mid : 0;
    const int ke  = half ? nt : mid;

    float mrun[4], lrun[4];
    f32x4 acc_o[4] = {};
    #pragma unroll
    for (int r = 0; r < 4; ++r) { mrun[r] = -1e30f; lrun[r] = 0.f; }

    if (kb < ke) {
      // ---- Q fragments (pre-scaled by 1/8) ----
      bf16x8 qf[2];
      {
        const unsigned short* qp = base + (size_t)(qw0 + lr) * QKV_LD + h * DH_ + 8 * lg;
        #pragma unroll
        for (int ks = 0; ks < 2; ++ks) {
          us8 qv = *(const us8*)(qp + 32 * ks);
          #pragma unroll
          for (int e = 0; e < 8; ++e) qf[ks][e] = (__bf16)(bf2f(qv[e]) * 0.125f);
        }
      }

      issue_loads(kb * 64);
      write_lds(0);
      __syncthreads();

      for (int kti = kb; kti < ke; ++kti) {
        const int k0 = kti * 64;
        const int cur = (kti - kb) & 1;

        if (kti + 1 < ke) issue_loads((kti + 1) * 64);

        if (k0 <= qw0 + 15) {  // wave not fully masked
          // ---- QK^T ----
          f32x4 sc[4] = {};
          #pragma unroll
          for (int kt = 0; kt < 4; ++kt)
            #pragma unroll
            for (int ks = 0; ks < 2; ++ks) {
              int row = kt * 16 + lr;
              bf16x8 kb_ = *(const bf16x8*)(smK[cur] + row * 128 +
                                            (((ks * 64) + 16 * lg) ^ ((row & 7) << 4)));
              sc[kt] = __builtin_amdgcn_mfma_f32_16x16x32_bf16(qf[ks], kb_, sc[kt], 0, 0, 0);
            }

          // ---- causal mask near diagonal ----
          if (k0 + 63 > qw0) {
            #pragma unroll
            for (int kt = 0; kt < 4; ++kt) {
              int kc = k0 + kt * 16 + lr;
              #pragma unroll
              for (int r = 0; r < 4; ++r)
                if (kc > qw0 + lg * 4 + r) sc[kt][r] = -1e30f;
            }
          }

          // ---- online softmax (rows across 16-lane groups) ----
          float mnew[4], alpha[4];
          #pragma unroll
          for (int r = 0; r < 4; ++r) {
            float v = fmaxf(fmaxf(sc[0][r], sc[1][r]), fmaxf(sc[2][r], sc[3][r]));
            #pragma unroll
            for (int off = 1; off < 16; off <<= 1) v = fmaxf(v, __shfl_xor(v, off));
            mnew[r] = fmaxf(mrun[r], v);
            alpha[r] = __expf(mrun[r] - mnew[r]);
            mrun[r] = mnew[r];
          }
          #pragma unroll
          for (int r = 0; r < 4; ++r) {
            float s = 0.f;
            #pragma unroll
            for (int kt = 0; kt < 4; ++kt) {
              float p = __expf(sc[kt][r] - mnew[r]);
              sc[kt][r] = p;
              s += p;
            }
            #pragma unroll
            for (int off = 1; off < 16; off <<= 1) s += __shfl_xor(s, off);
            lrun[r] = lrun[r] * alpha[r] + s;
          }

          // ---- write P (wave-private rows), rescale O ----
          #pragma unroll
          for (int kt = 0; kt < 4; ++kt)
            #pragma unroll
            for (int r = 0; r < 4; ++r) {
              int row = w * 16 + lg * 4 + r;
              *(unsigned short*)(smP + row * 128 + ((2 * (kt * 16 + lr)) ^ ((row & 7) << 4))) =
                  f2bf(sc[kt][r]);
            }
          #pragma unroll
          for (int dt = 0; dt < 4; ++dt)
            #pragma unroll
            for (int r = 0; r < 4; ++r) acc_o[dt][r] *= alpha[r];

          // ---- PV ----
          bf16x8 pa[2];
          #pragma unroll
          for (int ks = 0; ks < 2; ++ks) {
            int row = w * 16 + lr;
            pa[ks] = *(const bf16x8*)(smP + row * 128 +
                                      (((ks * 64) + 16 * lg) ^ ((lr & 7) << 4)));
          }
          #pragma unroll
          for (int dt = 0; dt < 4; ++dt)
            #pragma unroll
            for (int ks = 0; ks < 2; ++ks) {
              int row = dt * 16 + lr;
              bf16x8 vb = *(const bf16x8*)(smV[cur] + row * 128 +
                                           (((ks * 64) + 16 * lg) ^ ((row & 7) << 4)));
              acc_o[dt] = __builtin_amdgcn_mfma_f32_16x16x32_bf16(pa[ks], vb, acc_o[dt], 0, 0, 0);
            }
        }

        if (kti + 1 < ke) write_lds((kti - kb + 1) & 1);
        __syncthreads();
      }
    }

    // ---- write partial: normalized O (bf16) + (m,l) per row ----
    float inv[4];
    #pragma unroll
    for (int r = 0; r < 4; ++r) inv[r] = lrun[r] > 0.f ? 1.0f / lrun[r] : 0.f;
    #pragma unroll
    for (int dt = 0; dt < 4; ++dt)
      #pragma unroll
      for (int r = 0; r < 4; ++r) {
        int qrow = qw0 + lg * 4 + r;
        pO[(size_t)(bh * S_ + qrow) * DH_ + dt * 16 + lr] = f2bf(acc_o[dt][r] * inv[r]);
      }
    if (lr == 0) {
      #pragma unroll
      for (int r = 0; r < 4; ++r) {
        int qrow = qw0 + lg * 4 + r;
        pml_h[bh * S_ + qrow] = make_float2(mrun[r], lrun[r]);
      }
    }
  }
}

// ---------------- LSE merge of the two k-halves ----------------
__global__ __launch_bounds__(256) void attn_merge(
    const unsigned short* __restrict__ pO0, const unsigned short* __restrict__ pO1,
    const float2* __restrict__ pml, unsigned short* __restrict__ attn_bf) {
  const int idx = blockIdx.x * 256 + threadIdx.x;
  const int row = idx >> 3;          // 0..TOTROWS-1
  const int dg  = (idx & 7) * 8;     // d-octet
  const int bh = row >> 11, qrow = row & (S_ - 1);
  const int b = bh >> 4, h = bh & 15;
  float2 ml1 = pml[row];
  float2 ml2 = pml[TOTROWS + row];
  float m  = fmaxf(ml1.x, ml2.x);
  float w1 = ml1.y * __expf(ml1.x - m);
  float w2 = ml2.y * __expf(ml2.x - m);
  float inv = 1.0f / (w1 + w2);
  w1 *= inv; w2 *= inv;
  us8 o1 = *(const us8*)(pO0 + (size_t)row * DH_ + dg);
  us8 o2 = *(const us8*)(pO1 + (size_t)row * DH_ + dg);
  us8 o;
  #pragma unroll
  for (int e = 0; e < 8; ++e)
    o[e] = f2bf(w1 * bf2f(o1[e]) + w2 * bf2f(o2[e]));
  *(us8*)(attn_bf + ((size_t)(b * S_) + qrow) * D_ + h * DH_ + dg) = o;
}

extern "C" void kernel_launch(void* const* d_in, const int* in_sizes, int n_in,
                              void* d_out, int out_size, void* d_ws, size_t ws_size,
                              hipStream_t stream) {
  const float* x     = (const float*)d_in[0];
  const float* W_qkv = (const float*)d_in[1];
  const float* b_qkv = (const float*)d_in[2];
  const float* W_out = (const float*)d_in[3];
  const float* b_out = (const float*)d_in[4];
  float* out = (float*)d_out;

  char* ws = (char*)d_ws;
  unsigned short* qkv_bf  = (unsigned short*)ws;  ws += (size_t)M_ * QKV_LD * 2;   // 25.2 MB
  unsigned short* attn_bf = (unsigned short*)ws;  ws += (size_t)M_ * D_ * 2;       // 8.4 MB
  unsigned short* x_bf    = (unsigned short*)ws;  ws += (size_t)M_ * D_ * 2;       // 8.4 MB (reused as pO0)
  unsigned short* wqkvT   = (unsigned short*)ws;  ws += (size_t)QKV_LD * D_ * 2;   // 6.3 MB
  unsigned short* woutT   = (unsigned short*)ws;  ws += (size_t)D_ * D_ * 2;       // 2.1 MB
  unsigned short* pO1     = (unsigned short*)ws;  ws += (size_t)TOTROWS * DH_ * 2; // 8.4 MB
  float2*         pml     = (float2*)ws;                                            // 1.05 MB
  unsigned short* pO0     = x_bf;  // x_bf dead after QKV GEMM; attn overwrites it

  dim3 blk(256);
  conv_bf16<<<(M_ * D_ / 4 + 255) / 256, blk, 0, stream>>>(x, x_bf, M_ * D_ / 4);
  transpose_bf16<<<dim3(QKV_LD / 32, D_ / 32), blk, 0, stream>>>(W_qkv, wqkvT, D_, QKV_LD);
  transpose_bf16<<<dim3(D_ / 32, D_ / 32), blk, 0, stream>>>(W_out, woutT, D_, D_);
  gemm_bf16_tn<unsigned short><<<dim3(QKV_LD / 128, M_ / 128), blk, 0, stream>>>(
      x_bf, wqkvT, b_qkv, qkv_bf, QKV_LD, D_);
  // split-k causal attention: 1024 blocks (XCD-pinned bh, balanced pairs, 2 k-halves)
  attn_fwd_mfma<<<dim3(32, 32), blk, 0, stream>>>(qkv_bf, pO0, pO1, pml);
  attn_merge<<<(TOTROWS * 8) / 256, blk, 0, stream>>>(pO0, pO1, pml, attn_bf);
  gemm_bf16_tn<float><<<dim3(D_ / 128, M_ / 128), blk, 0, stream>>>(
      attn_bf, woutT, b_out, out, D_, D_);
}

// Round 11
// 138.852 us; speedup vs baseline: 1.1509x; 1.1509x over previous
//
#include <hip/hip_runtime.h>
#include <hip/hip_bf16.h>

#define B_  2
#define S_  2048
#define D_  1024
#define H_  16
#define DH_ 64
#define M_  (B_ * S_)       // 4096
#define QKV_LD (3 * D_)     // 3072

typedef __bf16 bf16x8 __attribute__((ext_vector_type(8)));
typedef float  f32x4  __attribute__((ext_vector_type(4)));
typedef unsigned short us4 __attribute__((ext_vector_type(4)));
typedef unsigned short us8 __attribute__((ext_vector_type(8)));

__device__ inline unsigned short f2bf(float f) {
  union { __bf16 h; unsigned short u; } cv; cv.h = (__bf16)f; return cv.u;
}
__device__ inline float bf2f(unsigned short u) {
  union { unsigned int i; float f; } cv; cv.i = ((unsigned int)u) << 16; return cv.f;
}
__device__ inline unsigned int pk2bf(float lo, float hi) {
  return (unsigned int)f2bf(lo) | ((unsigned int)f2bf(hi) << 16);
}
// typed stores: bf16 does the BIT conversion (round-3 bug: (unsigned short)v
// was an int conversion -> output was all-zero)
__device__ inline void cstore(float* p, float v) { *p = v; }
__device__ inline void cstore(unsigned short* p, float v) { *p = f2bf(v); }

__device__ inline void gload_lds16(const void* g, void* lds) {
  __builtin_amdgcn_global_load_lds(
      (const __attribute__((address_space(1))) unsigned int*)g,
      (__attribute__((address_space(3))) unsigned int*)lds, 16, 0, 0);
}

// ---------------- prep: fp32 -> bf16 (row-major copy) ----------------
__global__ __launch_bounds__(256) void conv_bf16(const float* __restrict__ in,
                                                 unsigned short* __restrict__ out, int n4) {
  int i = blockIdx.x * 256 + threadIdx.x;
  if (i >= n4) return;
  float4 v = ((const float4*)in)[i];
  us4 p = { f2bf(v.x), f2bf(v.y), f2bf(v.z), f2bf(v.w) };
  ((us4*)out)[i] = p;
}

// ---------------- prep: fp32 [K][N] -> bf16 [N][K] transpose ----------------
__global__ __launch_bounds__(256) void transpose_bf16(const float* __restrict__ W,
                                                      unsigned short* __restrict__ Wt,
                                                      int K, int N) {
  __shared__ float tile[32][33];
  const int t = threadIdx.x, tx = t & 31, ty = t >> 5;  // ty 0..7
  const int c0 = blockIdx.x * 32, r0 = blockIdx.y * 32;
  #pragma unroll
  for (int i = 0; i < 4; ++i)
    tile[ty + 8 * i][tx] = W[(size_t)(r0 + ty + 8 * i) * N + c0 + tx];
  __syncthreads();
  #pragma unroll
  for (int i = 0; i < 4; ++i)
    Wt[(size_t)(c0 + ty + 8 * i) * K + r0 + tx] = f2bf(tile[tx][ty + 8 * i]);
}

// ---------------- bf16 MFMA GEMM (m97 structure) ----------------
// C[M,N] = A[M,K] @ Bt[N,K]^T + bias.  128x128 tile, BK=32, 4 waves.
template<typename CT>
__global__ __launch_bounds__(256) void gemm_bf16_tn(
    const unsigned short* __restrict__ A,   // [M][K] bf16
    const unsigned short* __restrict__ Bt,  // [N][K] bf16
    const float* __restrict__ bias,
    CT* __restrict__ C, int N, int K) {
  __shared__ __align__(16) unsigned short smA[128 * 32];
  __shared__ __align__(16) unsigned short smB[128 * 32];
  const int t = threadIdx.x;
  const int w = t >> 6, l = t & 63;
  const int lg = l >> 4, lr = l & 15;
  const int row0 = blockIdx.y * 128, col0 = blockIdx.x * 128;
  const int wm = (w >> 1) * 64, wn = (w & 1) * 64;

  f32x4 acc[4][4] = {};

  for (int k0 = 0; k0 < K; k0 += 32) {
    __syncthreads();  // previous iteration's fragment reads complete
    #pragma unroll
    for (int i = 0; i < 2; ++i) {
      const int inst = 2 * w + i;
      const int r = inst * 16 + (l >> 2);
      const int cb = (l & 3) * 8;  // k-chunk of 8 bf16
      gload_lds16(A  + (size_t)(row0 + r) * K + k0 + cb, &smA[inst * 512]);
      gload_lds16(Bt + (size_t)(col0 + r) * K + k0 + cb, &smB[inst * 512]);
    }
    __syncthreads();  // waits vmcnt(0): tiles resident

    bf16x8 af[4], bfr[4];
    #pragma unroll
    for (int m = 0; m < 4; ++m)
      af[m] = *(const bf16x8*)&smA[(wm + m * 16 + lr) * 32 + lg * 8];
    #pragma unroll
    for (int n = 0; n < 4; ++n)
      bfr[n] = *(const bf16x8*)&smB[(wn + n * 16 + lr) * 32 + lg * 8];
    #pragma unroll
    for (int m = 0; m < 4; ++m)
      #pragma unroll
      for (int n = 0; n < 4; ++n)
        acc[m][n] = __builtin_amdgcn_mfma_f32_16x16x32_bf16(af[m], bfr[n], acc[m][n], 0, 0, 0);
  }

  #pragma unroll
  for (int m = 0; m < 4; ++m) {
    #pragma unroll
    for (int n = 0; n < 4; ++n) {
      const int col = col0 + wn + n * 16 + lr;
      const float bv = bias[col];
      #pragma unroll
      for (int r = 0; r < 4; ++r) {
        const int row = row0 + wm + m * 16 + lg * 4 + r;
        cstore(&C[(size_t)row * N + col], acc[m][n][r] + bv);
      }
    }
  }
}

// ---------------- Causal flash attention, bf16 MFMA ----------------
// Round-9 structure (XCD-pinned bh, balanced pairing, 83 us) + swapped QK^T:
// sc = mfma(K, Q) so lane l owns q-row (qw0 + l&15) and k-values
// {kt*16 + (l>>4)*4 + r}. Softmax reductions are 2 shfl_xor (16,32) instead
// of 4; P never touches LDS (packed to bf16 pairs in-register, redistributed
// to the PV A-fragment layout via 16 shfl + 8 cndmask). LDS: K/V dbuf only.
__global__ __launch_bounds__(256) void attn_fwd_mfma(
    const unsigned short* __restrict__ qkv, unsigned short* __restrict__ attn_out) {
  const int bid = blockIdx.x + gridDim.x * blockIdx.y;  // 0..511
  const int xcd = bid & 7;
  const int li  = bid >> 3;             // 0..63 within XCD
  const int bh  = xcd * 4 + (li >> 4);  // 4 bh per XCD
  const int x   = li & 15;              // balanced q-pair index 0..15
  const int b = bh / H_, h = bh % H_;
  const unsigned short* base = qkv + (size_t)b * S_ * QKV_LD;

  __shared__ __align__(16) char smK[2][64 * 128];  // K tile [k][d], XOR-swizzled
  __shared__ __align__(16) char smV[2][64 * 128];  // V^T tile [d][k]

  const int t  = threadIdx.x;
  const int w  = t >> 6;
  const int l  = t & 63;
  const int lg = l >> 4;
  const int lr = l & 15;

  const unsigned short* kbase = base + D_ + h * DH_;
  const unsigned short* vbase = base + 2 * D_ + h * DH_;

  // staging registers (T14 async split: issue early, LDS-write late)
  us8 kreg[2], vreg[2];
  const int kp  = (t & 31) * 2;    // V: pair of k-columns
  const int vdb = (t >> 5) * 8;    // V: 8 d-rows

  auto issue_loads = [&](int k0) {
    #pragma unroll
    for (int it = 0; it < 2; ++it) {
      int idx = t + it * 256;
      int r = idx >> 3, c = idx & 7;
      kreg[it] = *(const us8*)(kbase + (size_t)(k0 + r) * QKV_LD + c * 8);
    }
    vreg[0] = *(const us8*)(vbase + (size_t)(k0 + kp) * QKV_LD + vdb);
    vreg[1] = *(const us8*)(vbase + (size_t)(k0 + kp + 1) * QKV_LD + vdb);
  };
  auto write_lds = [&](int buf) {
    #pragma unroll
    for (int it = 0; it < 2; ++it) {
      int idx = t + it * 256;
      int r = idx >> 3, c = idx & 7;
      *(us8*)(smK[buf] + r * 128 + ((c * 16) ^ ((r & 7) << 4))) = kreg[it];
    }
    #pragma unroll
    for (int j = 0; j < 8; ++j) {
      int row = vdb + j;
      unsigned int pv = (unsigned int)vreg[0][j] | ((unsigned int)vreg[1][j] << 16);
      *(unsigned int*)(smV[buf] + row * 128 + ((2 * kp) ^ ((row & 7) << 4))) = pv;
    }
  };

  #pragma unroll 1
  for (int sel = 0; sel < 2; ++sel) {
    const int qt = sel ? (31 - x) : x;
    const int q0 = qt * 64;
    const int qw0 = q0 + w * 16;   // wave owns rows qw0..qw0+15

    // ---- Q fragments (pre-scaled by 1/8) ----
    bf16x8 qf[2];
    {
      const unsigned short* qp = base + (size_t)(qw0 + lr) * QKV_LD + h * DH_ + 8 * lg;
      #pragma unroll
      for (int ks = 0; ks < 2; ++ks) {
        us8 qv = *(const us8*)(qp + 32 * ks);
        #pragma unroll
        for (int e = 0; e < 8; ++e) qf[ks][e] = (__bf16)(bf2f(qv[e]) * 0.125f);
      }
    }

    float mrun = -1e30f, lrun = 0.f;   // this lane's q-row = qw0 + lr
    f32x4 acc_o[4] = {};

    const int ntiles = qt + 1;  // k tiles covering k <= q0+63
    issue_loads(0);
    write_lds(0);
    __syncthreads();

    for (int kti = 0; kti < ntiles; ++kti) {
      const int k0 = kti * 64;
      const int cur = kti & 1;

      if (kti + 1 < ntiles) issue_loads((kti + 1) * 64);

      if (k0 <= qw0 + 15) {  // wave not fully masked
        // ---- swapped QK^T: sc[kt] lane l = S[k0+kt*16+lg*4+r][qw0+lr] ----
        f32x4 sc[4] = {};
        #pragma unroll
        for (int kt = 0; kt < 4; ++kt)
          #pragma unroll
          for (int ks = 0; ks < 2; ++ks) {
            int row = kt * 16 + lr;
            bf16x8 kb_ = *(const bf16x8*)(smK[cur] + row * 128 +
                                          (((ks * 64) + 16 * lg) ^ ((row & 7) << 4)));
            sc[kt] = __builtin_amdgcn_mfma_f32_16x16x32_bf16(kb_, qf[ks], sc[kt], 0, 0, 0);
          }

        // ---- causal mask near diagonal (k rows, q cols now) ----
        if (k0 + 63 > qw0) {
          #pragma unroll
          for (int kt = 0; kt < 4; ++kt)
            #pragma unroll
            for (int r = 0; r < 4; ++r) {
              int kc = k0 + kt * 16 + lg * 4 + r;
              if (kc > qw0 + lr) sc[kt][r] = -1e30f;
            }
        }

        // ---- online softmax: lane owns one q-row; k split across lg lanes ----
        float v = sc[0][0];
        #pragma unroll
        for (int kt = 0; kt < 4; ++kt)
          #pragma unroll
          for (int r = 0; r < 4; ++r) v = fmaxf(v, sc[kt][r]);
        v = fmaxf(v, __shfl_xor(v, 16));
        v = fmaxf(v, __shfl_xor(v, 32));
        const float mnew = fmaxf(mrun, v);
        const float alpha = __expf(mrun - mnew);
        mrun = mnew;
        float s = 0.f;
        #pragma unroll
        for (int kt = 0; kt < 4; ++kt)
          #pragma unroll
          for (int r = 0; r < 4; ++r) {
            float p = __expf(sc[kt][r] - mnew);
            sc[kt][r] = p;
            s += p;
          }
        s += __shfl_xor(s, 16);
        s += __shfl_xor(s, 32);
        lrun = lrun * alpha + s;

        // ---- pack P to bf16 pairs; redistribute to PV A-fragment layout ----
        // lane holds P[k=kt*16+lg*4+{2j,2j+1}][q=lr] in P2[kt][j]; PV needs
        // pa[ks] lane l = P[q=lr][k=32ks+8lg+e]. Source lane for u32 q2 of
        // pa[ks]: 16*(2*(lg&1)+(q2>>1))+lr, kt = 2ks+(lg>>1) (select a/b).
        unsigned int P2[4][2];
        #pragma unroll
        for (int kt = 0; kt < 4; ++kt)
          #pragma unroll
          for (int j = 0; j < 2; ++j)
            P2[kt][j] = pk2bf(sc[kt][2 * j], sc[kt][2 * j + 1]);

        union { unsigned int u[4]; bf16x8 v8; } pa[2];
        #pragma unroll
        for (int ks = 0; ks < 2; ++ks)
          #pragma unroll
          for (int q2 = 0; q2 < 4; ++q2) {
            int src = 16 * (2 * (lg & 1) + (q2 >> 1)) + lr;
            unsigned int a = __shfl(P2[2 * ks][q2 & 1], src);
            unsigned int bsel = __shfl(P2[2 * ks + 1][q2 & 1], src);
            pa[ks].u[q2] = (lg & 2) ? bsel : a;
          }

        // ---- rescale O: alpha for O-row lg*4+r lives in lane lr'=lg*4+r ----
        float alphaO[4];
        #pragma unroll
        for (int r = 0; r < 4; ++r)
          alphaO[r] = __shfl(alpha, (l & 48) | (lg * 4 + r));
        #pragma unroll
        for (int dt = 0; dt < 4; ++dt)
          #pragma unroll
          for (int r = 0; r < 4; ++r) acc_o[dt][r] *= alphaO[r];

        // ---- PV ----
        #pragma unroll
        for (int dt = 0; dt < 4; ++dt)
          #pragma unroll
          for (int ks = 0; ks < 2; ++ks) {
            int row = dt * 16 + lr;
            bf16x8 vb = *(const bf16x8*)(smV[cur] + row * 128 +
                                         (((ks * 64) + 16 * lg) ^ ((row & 7) << 4)));
            acc_o[dt] = __builtin_amdgcn_mfma_f32_16x16x32_bf16(pa[ks].v8, vb, acc_o[dt], 0, 0, 0);
          }
      }

      if (kti + 1 < ntiles) write_lds(cur ^ 1);  // buf cur^1 free since last barrier
      __syncthreads();
    }

    // ---- normalize and write out (bf16) ----
    const float inv = 1.0f / lrun;   // for q-row qw0+lr
    float invO[4];
    #pragma unroll
    for (int r = 0; r < 4; ++r)
      invO[r] = __shfl(inv, (l & 48) | (lg * 4 + r));
    #pragma unroll
    for (int dt = 0; dt < 4; ++dt)
      #pragma unroll
      for (int r = 0; r < 4; ++r)
        attn_out[(size_t)(b * S_ + qw0 + lg * 4 + r) * D_ + h * DH_ + dt * 16 + lr] =
            f2bf(acc_o[dt][r] * invO[r]);
  }
}

extern "C" void kernel_launch(void* const* d_in, const int* in_sizes, int n_in,
                              void* d_out, int out_size, void* d_ws, size_t ws_size,
                              hipStream_t stream) {
  const float* x     = (const float*)d_in[0];
  const float* W_qkv = (const float*)d_in[1];
  const float* b_qkv = (const float*)d_in[2];
  const float* W_out = (const float*)d_in[3];
  const float* b_out = (const float*)d_in[4];
  float* out = (float*)d_out;

  char* ws = (char*)d_ws;
  unsigned short* qkv_bf  = (unsigned short*)ws;  ws += (size_t)M_ * QKV_LD * 2;
  unsigned short* attn_bf = (unsigned short*)ws;  ws += (size_t)M_ * D_ * 2;
  unsigned short* x_bf    = (unsigned short*)ws;  ws += (size_t)M_ * D_ * 2;
  unsigned short* wqkvT   = (unsigned short*)ws;  ws += (size_t)QKV_LD * D_ * 2;
  unsigned short* woutT   = (unsigned short*)ws;

  dim3 blk(256);
  conv_bf16<<<(M_ * D_ / 4 + 255) / 256, blk, 0, stream>>>(x, x_bf, M_ * D_ / 4);
  transpose_bf16<<<dim3(QKV_LD / 32, D_ / 32), blk, 0, stream>>>(W_qkv, wqkvT, D_, QKV_LD);
  transpose_bf16<<<dim3(D_ / 32, D_ / 32), blk, 0, stream>>>(W_out, woutT, D_, D_);
  gemm_bf16_tn<unsigned short><<<dim3(QKV_LD / 128, M_ / 128), blk, 0, stream>>>(
      x_bf, wqkvT, b_qkv, qkv_bf, QKV_LD, D_);
  // balanced causal pairing + XCD-pinned bh (remap inside kernel)
  attn_fwd_mfma<<<dim3(S_ / 64 / 2, B_ * H_), blk, 0, stream>>>(qkv_bf, attn_bf);
  gemm_bf16_tn<float><<<dim3(D_ / 128, M_ / 128), blk, 0, stream>>>(
      attn_bf, woutT, b_out, out, D_, D_);
}

// Round 12
// 127.736 us; speedup vs baseline: 1.2511x; 1.0870x over previous
//
#include <hip/hip_runtime.h>
#include <hip/hip_bf16.h>

#define B_  2
#define S_  2048
#define D_  1024
#define H_  16
#define DH_ 64
#define M_  (B_ * S_)       // 4096
#define QKV_LD (3 * D_)     // 3072

typedef __bf16 bf16x8 __attribute__((ext_vector_type(8)));
typedef float  f32x4  __attribute__((ext_vector_type(4)));
typedef unsigned short us4 __attribute__((ext_vector_type(4)));
typedef unsigned short us8 __attribute__((ext_vector_type(8)));

__device__ inline unsigned short f2bf(float f) {
  union { __bf16 h; unsigned short u; } cv; cv.h = (__bf16)f; return cv.u;
}
__device__ inline float bf2f(unsigned short u) {
  union { unsigned int i; float f; } cv; cv.i = ((unsigned int)u) << 16; return cv.f;
}
__device__ inline unsigned int pk2bf(float lo, float hi) {
  return (unsigned int)f2bf(lo) | ((unsigned int)f2bf(hi) << 16);
}
// typed stores: bf16 does the BIT conversion (round-3 bug: (unsigned short)v
// was an int conversion -> output was all-zero)
__device__ inline void cstore(float* p, float v) { *p = v; }
__device__ inline void cstore(unsigned short* p, float v) { *p = f2bf(v); }

__device__ inline void gload_lds16(const void* g, void* lds) {
  __builtin_amdgcn_global_load_lds(
      (const __attribute__((address_space(1))) unsigned int*)g,
      (__attribute__((address_space(3))) unsigned int*)lds, 16, 0, 0);
}

// ---------------- fused prep: x->bf16, W_qkv^T->bf16, W_out^T->bf16 ----------------
__global__ __launch_bounds__(256) void prep_all(
    const float* __restrict__ x, unsigned short* __restrict__ x_bf,
    const float* __restrict__ W_qkv, unsigned short* __restrict__ wqkvT,
    const float* __restrict__ W_out, unsigned short* __restrict__ woutT) {
  __shared__ float tile[32][33];
  const int blk = blockIdx.x;
  const int t = threadIdx.x;
  if (blk < 4096) {                       // conv x -> bf16, 4 floats/thread
    int i = blk * 256 + t;
    float4 v = ((const float4*)x)[i];
    us4 p = { f2bf(v.x), f2bf(v.y), f2bf(v.z), f2bf(v.w) };
    ((us4*)x_bf)[i] = p;
    return;
  }
  const float* W; unsigned short* Wt; int K, N, bi;
  if (blk < 4096 + 3072) { bi = blk - 4096; W = W_qkv; Wt = wqkvT; K = D_; N = QKV_LD; }
  else                   { bi = blk - 7168; W = W_out; Wt = woutT; K = D_; N = D_; }
  const int bx = bi % (N / 32), by = bi / (N / 32);
  const int tx = t & 31, ty = t >> 5;
  const int c0 = bx * 32, r0 = by * 32;
  #pragma unroll
  for (int i = 0; i < 4; ++i)
    tile[ty + 8 * i][tx] = W[(size_t)(r0 + ty + 8 * i) * N + c0 + tx];
  __syncthreads();
  #pragma unroll
  for (int i = 0; i < 4; ++i)
    Wt[(size_t)(c0 + ty + 8 * i) * K + r0 + tx] = f2bf(tile[tx][ty + 8 * i]);
}

// ---------------- bf16 MFMA GEMM (m97 structure) ----------------
// C[M,N] = A[M,K] @ Bt[N,K]^T + bias.  128x128 tile, BK=32, 4 waves.
template<typename CT>
__global__ __launch_bounds__(256) void gemm_bf16_tn(
    const unsigned short* __restrict__ A,   // [M][K] bf16
    const unsigned short* __restrict__ Bt,  // [N][K] bf16
    const float* __restrict__ bias,
    CT* __restrict__ C, int N, int K) {
  __shared__ __align__(16) unsigned short smA[128 * 32];
  __shared__ __align__(16) unsigned short smB[128 * 32];
  const int t = threadIdx.x;
  const int w = t >> 6, l = t & 63;
  const int lg = l >> 4, lr = l & 15;
  const int row0 = blockIdx.y * 128, col0 = blockIdx.x * 128;
  const int wm = (w >> 1) * 64, wn = (w & 1) * 64;

  f32x4 acc[4][4] = {};

  for (int k0 = 0; k0 < K; k0 += 32) {
    __syncthreads();  // previous iteration's fragment reads complete
    #pragma unroll
    for (int i = 0; i < 2; ++i) {
      const int inst = 2 * w + i;
      const int r = inst * 16 + (l >> 2);
      const int cb = (l & 3) * 8;  // k-chunk of 8 bf16
      gload_lds16(A  + (size_t)(row0 + r) * K + k0 + cb, &smA[inst * 512]);
      gload_lds16(Bt + (size_t)(col0 + r) * K + k0 + cb, &smB[inst * 512]);
    }
    __syncthreads();  // waits vmcnt(0): tiles resident

    bf16x8 af[4], bfr[4];
    #pragma unroll
    for (int m = 0; m < 4; ++m)
      af[m] = *(const bf16x8*)&smA[(wm + m * 16 + lr) * 32 + lg * 8];
    #pragma unroll
    for (int n = 0; n < 4; ++n)
      bfr[n] = *(const bf16x8*)&smB[(wn + n * 16 + lr) * 32 + lg * 8];
    #pragma unroll
    for (int m = 0; m < 4; ++m)
      #pragma unroll
      for (int n = 0; n < 4; ++n)
        acc[m][n] = __builtin_amdgcn_mfma_f32_16x16x32_bf16(af[m], bfr[n], acc[m][n], 0, 0, 0);
  }

  #pragma unroll
  for (int m = 0; m < 4; ++m) {
    #pragma unroll
    for (int n = 0; n < 4; ++n) {
      const int col = col0 + wn + n * 16 + lr;
      const float bv = bias[col];
      #pragma unroll
      for (int r = 0; r < 4; ++r) {
        const int row = row0 + wm + m * 16 + lg * 4 + r;
        cstore(&C[(size_t)row * N + col], acc[m][n][r] + bv);
      }
    }
  }
}

// ---------------- Causal flash attention, bf16 MFMA ----------------
// Round-11 structure (XCD-pinned bh, balanced pairing, swapped QK^T) with
// sigma-permuted K staging: LDS K-row rho holds global k-row
// sigma(rho) = 32*(rho>>5) + 8*((rho>>2)&3) + 4*((rho>>4)&1) + (rho&3),
// chosen so sc[kt][r] (true k = k0+32*(kt>>1)+8*lg+4*(kt&1)+r) packs
// IN-LANE into PV's A-fragment: pa[ks] = {sc[2ks][0..3], sc[2ks+1][0..3]}.
// Zero P shuffles. Softmax in log2 domain (log2e folded into Q scale,
// exp2f = bare v_exp_f32) + T13 defer-max (skip rescale when growth <= 8).
__global__ __launch_bounds__(256) void attn_fwd_mfma(
    const unsigned short* __restrict__ qkv, unsigned short* __restrict__ attn_out) {
  const int bid = blockIdx.x + gridDim.x * blockIdx.y;  // 0..511
  const int xcd = bid & 7;
  const int li  = bid >> 3;             // 0..63 within XCD
  const int bh  = xcd * 4 + (li >> 4);  // 4 bh per XCD
  const int x   = li & 15;              // balanced q-pair index 0..15
  const int b = bh / H_, h = bh % H_;
  const unsigned short* base = qkv + (size_t)b * S_ * QKV_LD;

  __shared__ __align__(16) char smK[2][64 * 128];  // K tile [sigma-row][d], XOR-swizzled
  __shared__ __align__(16) char smV[2][64 * 128];  // V^T tile [d][k]

  const int t  = threadIdx.x;
  const int w  = t >> 6;
  const int l  = t & 63;
  const int lg = l >> 4;
  const int lr = l & 15;

  const unsigned short* kbase = base + D_ + h * DH_;
  const unsigned short* vbase = base + 2 * D_ + h * DH_;

  // staging registers (T14 async split: issue early, LDS-write late)
  us8 kreg[2], vreg[2];
  const int kp  = (t & 31) * 2;    // V: pair of k-columns
  const int vdb = (t >> 5) * 8;    // V: 8 d-rows

  auto issue_loads = [&](int k0) {
    #pragma unroll
    for (int it = 0; it < 2; ++it) {
      int idx = t + it * 256;
      int r = idx >> 3, c = idx & 7;
      kreg[it] = *(const us8*)(kbase + (size_t)(k0 + r) * QKV_LD + c * 8);
    }
    vreg[0] = *(const us8*)(vbase + (size_t)(k0 + kp) * QKV_LD + vdb);
    vreg[1] = *(const us8*)(vbase + (size_t)(k0 + kp + 1) * QKV_LD + vdb);
  };
  auto write_lds = [&](int buf) {
    #pragma unroll
    for (int it = 0; it < 2; ++it) {
      int idx = t + it * 256;
      int r = idx >> 3, c = idx & 7;
      // sigma^-1: global k-row r -> LDS row rho (pure bit permutation)
      int rho = (r & 0x23) | ((r & 0x04) << 2) | ((r & 0x18) >> 1);
      *(us8*)(smK[buf] + rho * 128 + ((c * 16) ^ ((rho & 7) << 4))) = kreg[it];
    }
    #pragma unroll
    for (int j = 0; j < 8; ++j) {
      int row = vdb + j;
      unsigned int pv = (unsigned int)vreg[0][j] | ((unsigned int)vreg[1][j] << 16);
      *(unsigned int*)(smV[buf] + row * 128 + ((2 * kp) ^ ((row & 7) << 4))) = pv;
    }
  };

  #pragma unroll 1
  for (int sel = 0; sel < 2; ++sel) {
    const int qt = sel ? (31 - x) : x;
    const int q0 = qt * 64;
    const int qw0 = q0 + w * 16;   // wave owns rows qw0..qw0+15

    // ---- Q fragments (scale = 1/8 * log2(e): softmax in log2 domain) ----
    bf16x8 qf[2];
    {
      const unsigned short* qp = base + (size_t)(qw0 + lr) * QKV_LD + h * DH_ + 8 * lg;
      #pragma unroll
      for (int ks = 0; ks < 2; ++ks) {
        us8 qv = *(const us8*)(qp + 32 * ks);
        #pragma unroll
        for (int e = 0; e < 8; ++e) qf[ks][e] = (__bf16)(bf2f(qv[e]) * 0.18033688f);
      }
    }

    float mrun = -1e30f, lrun = 0.f;   // this lane's q-row = qw0 + lr
    f32x4 acc_o[4] = {};

    const int ntiles = qt + 1;  // k tiles covering k <= q0+63
    issue_loads(0);
    write_lds(0);
    __syncthreads();

    for (int kti = 0; kti < ntiles; ++kti) {
      const int k0 = kti * 64;
      const int cur = kti & 1;

      if (kti + 1 < ntiles) issue_loads((kti + 1) * 64);

      if (k0 <= qw0 + 15) {  // wave not fully masked
        // ---- swapped QK^T on sigma-permuted K rows ----
        f32x4 sc[4] = {};
        #pragma unroll
        for (int kt = 0; kt < 4; ++kt)
          #pragma unroll
          for (int ks = 0; ks < 2; ++ks) {
            int row = kt * 16 + lr;
            bf16x8 kb_ = *(const bf16x8*)(smK[cur] + row * 128 +
                                          (((ks * 64) + 16 * lg) ^ ((row & 7) << 4)));
            sc[kt] = __builtin_amdgcn_mfma_f32_16x16x32_bf16(kb_, qf[ks], sc[kt], 0, 0, 0);
          }

        // ---- causal mask: sc[kt][r] true k = k0+32*(kt>>1)+8*lg+4*(kt&1)+r ----
        if (k0 + 63 > qw0) {
          #pragma unroll
          for (int kt = 0; kt < 4; ++kt)
            #pragma unroll
            for (int r = 0; r < 4; ++r) {
              int kc = k0 + ((kt >> 1) << 5) + (lg << 3) + ((kt & 1) << 2) + r;
              if (kc > qw0 + lr) sc[kt][r] = -1e30f;
            }
        }

        // ---- online softmax (log2 domain); lane owns one q-row ----
        float v = fmaxf(fmaxf(sc[0][0], sc[0][1]), fmaxf(sc[0][2], sc[0][3]));
        #pragma unroll
        for (int kt = 1; kt < 4; ++kt)
          v = fmaxf(v, fmaxf(fmaxf(sc[kt][0], sc[kt][1]), fmaxf(sc[kt][2], sc[kt][3])));
        v = fmaxf(v, __shfl_xor(v, 16));
        v = fmaxf(v, __shfl_xor(v, 32));
        // T13 defer-max: skip rescale while growth <= 8 (p bounded by 2^8)
        if (!__all(v <= mrun + 8.0f)) {
          const float mnew = fmaxf(mrun, v);
          const float alpha = exp2f(mrun - mnew);
          mrun = mnew;
          float alphaO[4];
          #pragma unroll
          for (int r = 0; r < 4; ++r)
            alphaO[r] = __shfl(alpha, (l & 48) | (lg * 4 + r));
          #pragma unroll
          for (int dt = 0; dt < 4; ++dt)
            #pragma unroll
            for (int r = 0; r < 4; ++r) acc_o[dt][r] *= alphaO[r];
          lrun *= alpha;
        }
        float s = 0.f;
        #pragma unroll
        for (int kt = 0; kt < 4; ++kt)
          #pragma unroll
          for (int r = 0; r < 4; ++r) {
            float p = exp2f(sc[kt][r] - mrun);
            sc[kt][r] = p;
            s += p;
          }
        s += __shfl_xor(s, 16);
        s += __shfl_xor(s, 32);
        lrun += s;

        // ---- PV A-fragments: pure in-lane pack (sigma made slots line up) ----
        union { unsigned int u[4]; bf16x8 v8; } pa[2];
        #pragma unroll
        for (int ks = 0; ks < 2; ++ks) {
          pa[ks].u[0] = pk2bf(sc[2 * ks][0], sc[2 * ks][1]);
          pa[ks].u[1] = pk2bf(sc[2 * ks][2], sc[2 * ks][3]);
          pa[ks].u[2] = pk2bf(sc[2 * ks + 1][0], sc[2 * ks + 1][1]);
          pa[ks].u[3] = pk2bf(sc[2 * ks + 1][2], sc[2 * ks + 1][3]);
        }

        // ---- PV ----
        #pragma unroll
        for (int dt = 0; dt < 4; ++dt)
          #pragma unroll
          for (int ks = 0; ks < 2; ++ks) {
            int row = dt * 16 + lr;
            bf16x8 vb = *(const bf16x8*)(smV[cur] + row * 128 +
                                         (((ks * 64) + 16 * lg) ^ ((row & 7) << 4)));
            acc_o[dt] = __builtin_amdgcn_mfma_f32_16x16x32_bf16(pa[ks].v8, vb, acc_o[dt], 0, 0, 0);
          }
      }

      if (kti + 1 < ntiles) write_lds(cur ^ 1);  // buf cur^1 free since last barrier
      __syncthreads();
    }

    // ---- normalize and write out (bf16) ----
    const float inv = 1.0f / lrun;   // for q-row qw0+lr
    float invO[4];
    #pragma unroll
    for (int r = 0; r < 4; ++r)
      invO[r] = __shfl(inv, (l & 48) | (lg * 4 + r));
    #pragma unroll
    for (int dt = 0; dt < 4; ++dt)
      #pragma unroll
      for (int r = 0; r < 4; ++r)
        attn_out[(size_t)(b * S_ + qw0 + lg * 4 + r) * D_ + h * DH_ + dt * 16 + lr] =
            f2bf(acc_o[dt][r] * invO[r]);
  }
}

extern "C" void kernel_launch(void* const* d_in, const int* in_sizes, int n_in,
                              void* d_out, int out_size, void* d_ws, size_t ws_size,
                              hipStream_t stream) {
  const float* x     = (const float*)d_in[0];
  const float* W_qkv = (const float*)d_in[1];
  const float* b_qkv = (const float*)d_in[2];
  const float* W_out = (const float*)d_in[3];
  const float* b_out = (const float*)d_in[4];
  float* out = (float*)d_out;

  char* ws = (char*)d_ws;
  unsigned short* qkv_bf  = (unsigned short*)ws;  ws += (size_t)M_ * QKV_LD * 2;
  unsigned short* attn_bf = (unsigned short*)ws;  ws += (size_t)M_ * D_ * 2;
  unsigned short* x_bf    = (unsigned short*)ws;  ws += (size_t)M_ * D_ * 2;
  unsigned short* wqkvT   = (unsigned short*)ws;  ws += (size_t)QKV_LD * D_ * 2;
  unsigned short* woutT   = (unsigned short*)ws;

  dim3 blk(256);
  // fused prep: conv (4096 blocks) + W_qkv^T (3072) + W_out^T (1024)
  prep_all<<<4096 + 3072 + 1024, blk, 0, stream>>>(x, x_bf, W_qkv, wqkvT, W_out, woutT);
  gemm_bf16_tn<unsigned short><<<dim3(QKV_LD / 128, M_ / 128), blk, 0, stream>>>(
      x_bf, wqkvT, b_qkv, qkv_bf, QKV_LD, D_);
  // balanced causal pairing + XCD-pinned bh (remap inside kernel)
  attn_fwd_mfma<<<dim3(S_ / 64 / 2, B_ * H_), blk, 0, stream>>>(qkv_bf, attn_bf);
  gemm_bf16_tn<float><<<dim3(D_ / 128, M_ / 128), blk, 0, stream>>>(
      attn_bf, woutT, b_out, out, D_, D_);
}

// Round 13
// 121.839 us; speedup vs baseline: 1.3116x; 1.0484x over previous
//
#include <hip/hip_runtime.h>
#include <hip/hip_bf16.h>

#define B_  2
#define S_  2048
#define D_  1024
#define H_  16
#define DH_ 64
#define M_  (B_ * S_)       // 4096
#define QKV_LD (3 * D_)     // 3072

typedef __bf16 bf16x8 __attribute__((ext_vector_type(8)));
typedef float  f32x4  __attribute__((ext_vector_type(4)));
typedef unsigned short us4 __attribute__((ext_vector_type(4)));
typedef unsigned short us8 __attribute__((ext_vector_type(8)));

__device__ inline unsigned short f2bf(float f) {
  union { __bf16 h; unsigned short u; } cv; cv.h = (__bf16)f; return cv.u;
}
__device__ inline float bf2f(unsigned short u) {
  union { unsigned int i; float f; } cv; cv.i = ((unsigned int)u) << 16; return cv.f;
}
__device__ inline unsigned int pk2bf(float lo, float hi) {
  return (unsigned int)f2bf(lo) | ((unsigned int)f2bf(hi) << 16);
}
// typed stores: bf16 does the BIT conversion (round-3 bug: (unsigned short)v
// was an int conversion -> output was all-zero)
__device__ inline void cstore(float* p, float v) { *p = v; }
__device__ inline void cstore(unsigned short* p, float v) { *p = f2bf(v); }

__device__ inline void gload_lds16(const void* g, void* lds) {
  __builtin_amdgcn_global_load_lds(
      (const __attribute__((address_space(1))) unsigned int*)g,
      (__attribute__((address_space(3))) unsigned int*)lds, 16, 0, 0);
}

// ---------------- fused prep: x->bf16, W_qkv^T->bf16, W_out^T->bf16 ----------------
__global__ __launch_bounds__(256) void prep_all(
    const float* __restrict__ x, unsigned short* __restrict__ x_bf,
    const float* __restrict__ W_qkv, unsigned short* __restrict__ wqkvT,
    const float* __restrict__ W_out, unsigned short* __restrict__ woutT) {
  __shared__ float tile[32][33];
  const int blk = blockIdx.x;
  const int t = threadIdx.x;
  if (blk < 4096) {                       // conv x -> bf16, 4 floats/thread
    int i = blk * 256 + t;
    float4 v = ((const float4*)x)[i];
    us4 p = { f2bf(v.x), f2bf(v.y), f2bf(v.z), f2bf(v.w) };
    ((us4*)x_bf)[i] = p;
    return;
  }
  const float* W; unsigned short* Wt; int K, N, bi;
  if (blk < 4096 + 3072) { bi = blk - 4096; W = W_qkv; Wt = wqkvT; K = D_; N = QKV_LD; }
  else                   { bi = blk - 7168; W = W_out; Wt = woutT; K = D_; N = D_; }
  const int bx = bi % (N / 32), by = bi / (N / 32);
  const int tx = t & 31, ty = t >> 5;
  const int c0 = bx * 32, r0 = by * 32;
  #pragma unroll
  for (int i = 0; i < 4; ++i)
    tile[ty + 8 * i][tx] = W[(size_t)(r0 + ty + 8 * i) * N + c0 + tx];
  __syncthreads();
  #pragma unroll
  for (int i = 0; i < 4; ++i)
    Wt[(size_t)(c0 + ty + 8 * i) * K + r0 + tx] = f2bf(tile[tx][ty + 8 * i]);
}

// ---------------- bf16 MFMA GEMM (m97 structure) ----------------
// C[M,N] = A[M,K] @ Bt[N,K]^T + bias.  128x128 tile, BK=32, 4 waves.
template<typename CT>
__global__ __launch_bounds__(256) void gemm_bf16_tn(
    const unsigned short* __restrict__ A,   // [M][K] bf16
    const unsigned short* __restrict__ Bt,  // [N][K] bf16
    const float* __restrict__ bias,
    CT* __restrict__ C, int N, int K) {
  __shared__ __align__(16) unsigned short smA[128 * 32];
  __shared__ __align__(16) unsigned short smB[128 * 32];
  const int t = threadIdx.x;
  const int w = t >> 6, l = t & 63;
  const int lg = l >> 4, lr = l & 15;
  const int row0 = blockIdx.y * 128, col0 = blockIdx.x * 128;
  const int wm = (w >> 1) * 64, wn = (w & 1) * 64;

  f32x4 acc[4][4] = {};

  for (int k0 = 0; k0 < K; k0 += 32) {
    __syncthreads();  // previous iteration's fragment reads complete
    #pragma unroll
    for (int i = 0; i < 2; ++i) {
      const int inst = 2 * w + i;
      const int r = inst * 16 + (l >> 2);
      const int cb = (l & 3) * 8;  // k-chunk of 8 bf16
      gload_lds16(A  + (size_t)(row0 + r) * K + k0 + cb, &smA[inst * 512]);
      gload_lds16(Bt + (size_t)(col0 + r) * K + k0 + cb, &smB[inst * 512]);
    }
    __syncthreads();  // waits vmcnt(0): tiles resident

    bf16x8 af[4], bfr[4];
    #pragma unroll
    for (int m = 0; m < 4; ++m)
      af[m] = *(const bf16x8*)&smA[(wm + m * 16 + lr) * 32 + lg * 8];
    #pragma unroll
    for (int n = 0; n < 4; ++n)
      bfr[n] = *(const bf16x8*)&smB[(wn + n * 16 + lr) * 32 + lg * 8];
    #pragma unroll
    for (int m = 0; m < 4; ++m)
      #pragma unroll
      for (int n = 0; n < 4; ++n)
        acc[m][n] = __builtin_amdgcn_mfma_f32_16x16x32_bf16(af[m], bfr[n], acc[m][n], 0, 0, 0);
  }

  #pragma unroll
  for (int m = 0; m < 4; ++m) {
    #pragma unroll
    for (int n = 0; n < 4; ++n) {
      const int col = col0 + wn + n * 16 + lr;
      const float bv = bias[col];
      #pragma unroll
      for (int r = 0; r < 4; ++r) {
        const int row = row0 + wm + m * 16 + lg * 4 + r;
        cstore(&C[(size_t)row * N + col], acc[m][n][r] + bv);
      }
    }
  }
}

// ---------------- Causal flash attention, bf16 MFMA ----------------
// 512 blocks x 512 threads (8 waves). Waves 0-3 own q-tile lo=x, waves 4-7
// own hi=31-x, processed CONCURRENTLY in one k-loop of 32-x tiles (lo
// computes only while kti <= x, wave-uniform). K/V staged once per tile for
// both q-tiles, by threads <256 only (the lo waves, which idle past x) --
// soft producer/consumer. Ascending-x dispatch = longest-first (LPT
// balance). XCD-pinned bh; sigma-permuted K rows (PV A-frag packs in-lane,
// zero shuffles); log2-domain softmax + T13 defer-max; LDS dbuf; 1 barrier
// per tile. sigma(rho) = 32*(rho>>5)+8*((rho>>2)&3)+4*((rho>>4)&1)+(rho&3).
__global__ __launch_bounds__(512, 4) void attn_fwd_mfma(
    const unsigned short* __restrict__ qkv, unsigned short* __restrict__ attn_out) {
  const int bid = blockIdx.x;           // 0..511
  const int xcd = bid & 7;
  const int li  = bid >> 3;             // 0..63 within XCD
  const int bh  = xcd * 4 + (li >> 4);  // 4 bh per XCD
  const int x   = li & 15;              // pair index: lo q-tile x, hi 31-x
  const int b = bh / H_, h = bh % H_;
  const unsigned short* base = qkv + (size_t)b * S_ * QKV_LD;

  __shared__ __align__(16) char smK[2][64 * 128];  // K tile [sigma-row][d], XOR-swizzled
  __shared__ __align__(16) char smV[2][64 * 128];  // V^T tile [d][k]

  const int t  = threadIdx.x;           // 0..511
  const int w  = t >> 6;                // 0..7
  const bool lo = (w < 4);
  const int wq = w & 3;
  const int l  = t & 63;
  const int lg = l >> 4;
  const int lr = l & 15;

  const int qt  = lo ? x : (31 - x);
  const int qw0 = qt * 64 + wq * 16;    // wave owns rows qw0..qw0+15

  const unsigned short* kbase = base + D_ + h * DH_;
  const unsigned short* vbase = base + 2 * D_ + h * DH_;

  // staging (threads <256 only): T14 async split, issue early / write late
  us8 kreg[2], vreg[2];
  const int kp  = (t & 31) * 2;          // V: pair of k-columns
  const int vdb = ((t >> 5) & 7) * 8;    // V: 8 d-rows

  auto issue_loads = [&](int k0) {
    #pragma unroll
    for (int it = 0; it < 2; ++it) {
      int idx = t + it * 256;
      int r = idx >> 3, c = idx & 7;
      kreg[it] = *(const us8*)(kbase + (size_t)(k0 + r) * QKV_LD + c * 8);
    }
    vreg[0] = *(const us8*)(vbase + (size_t)(k0 + kp) * QKV_LD + vdb);
    vreg[1] = *(const us8*)(vbase + (size_t)(k0 + kp + 1) * QKV_LD + vdb);
  };
  auto write_lds = [&](int buf) {
    #pragma unroll
    for (int it = 0; it < 2; ++it) {
      int idx = t + it * 256;
      int r = idx >> 3, c = idx & 7;
      // sigma^-1: global k-row r -> LDS row rho (pure bit permutation)
      int rho = (r & 0x23) | ((r & 0x04) << 2) | ((r & 0x18) >> 1);
      *(us8*)(smK[buf] + rho * 128 + ((c * 16) ^ ((rho & 7) << 4))) = kreg[it];
    }
    #pragma unroll
    for (int j = 0; j < 8; ++j) {
      int row = vdb + j;
      unsigned int pv = (unsigned int)vreg[0][j] | ((unsigned int)vreg[1][j] << 16);
      *(unsigned int*)(smV[buf] + row * 128 + ((2 * kp) ^ ((row & 7) << 4))) = pv;
    }
  };

  // ---- Q fragments (scale = 1/8 * log2(e): softmax in log2 domain) ----
  bf16x8 qf[2];
  {
    const unsigned short* qp = base + (size_t)(qw0 + lr) * QKV_LD + h * DH_ + 8 * lg;
    #pragma unroll
    for (int ks = 0; ks < 2; ++ks) {
      us8 qv = *(const us8*)(qp + 32 * ks);
      #pragma unroll
      for (int e = 0; e < 8; ++e) qf[ks][e] = (__bf16)(bf2f(qv[e]) * 0.18033688f);
    }
  }

  float mrun = -1e30f, lrun = 0.f;   // this lane's q-row = qw0 + lr
  f32x4 acc_o[4] = {};

  const int ntiles = 32 - x;   // hi's tile count (superset of lo's x+1)
  if (t < 256) { issue_loads(0); write_lds(0); }
  __syncthreads();

  for (int kti = 0; kti < ntiles; ++kti) {
    const int k0 = kti * 64;
    const int cur = kti & 1;

    if (t < 256 && kti + 1 < ntiles) issue_loads((kti + 1) * 64);

    const bool active = lo ? (kti <= x) : true;   // wave-uniform
    if (active) {
      // ---- swapped QK^T on sigma-permuted K rows ----
      f32x4 sc[4] = {};
      #pragma unroll
      for (int kt = 0; kt < 4; ++kt)
        #pragma unroll
        for (int ks = 0; ks < 2; ++ks) {
          int row = kt * 16 + lr;
          bf16x8 kb_ = *(const bf16x8*)(smK[cur] + row * 128 +
                                        (((ks * 64) + 16 * lg) ^ ((row & 7) << 4)));
          sc[kt] = __builtin_amdgcn_mfma_f32_16x16x32_bf16(kb_, qf[ks], sc[kt], 0, 0, 0);
        }

      // ---- causal mask: sc[kt][r] true k = k0+32*(kt>>1)+8*lg+4*(kt&1)+r ----
      if (k0 + 63 > qw0) {
        #pragma unroll
        for (int kt = 0; kt < 4; ++kt)
          #pragma unroll
          for (int r = 0; r < 4; ++r) {
            int kc = k0 + ((kt >> 1) << 5) + (lg << 3) + ((kt & 1) << 2) + r;
            if (kc > qw0 + lr) sc[kt][r] = -1e30f;
          }
      }

      // ---- online softmax (log2 domain); lane owns one q-row ----
      float v = fmaxf(fmaxf(sc[0][0], sc[0][1]), fmaxf(sc[0][2], sc[0][3]));
      #pragma unroll
      for (int kt = 1; kt < 4; ++kt)
        v = fmaxf(v, fmaxf(fmaxf(sc[kt][0], sc[kt][1]), fmaxf(sc[kt][2], sc[kt][3])));
      v = fmaxf(v, __shfl_xor(v, 16));
      v = fmaxf(v, __shfl_xor(v, 32));
      // T13 defer-max: skip rescale while growth <= 8 (p bounded by 2^8)
      if (!__all(v <= mrun + 8.0f)) {
        const float mnew = fmaxf(mrun, v);
        const float alpha = exp2f(mrun - mnew);
        mrun = mnew;
        float alphaO[4];
        #pragma unroll
        for (int r = 0; r < 4; ++r)
          alphaO[r] = __shfl(alpha, (l & 48) | (lg * 4 + r));
        #pragma unroll
        for (int dt = 0; dt < 4; ++dt)
          #pragma unroll
          for (int r = 0; r < 4; ++r) acc_o[dt][r] *= alphaO[r];
        lrun *= alpha;
      }
      float s = 0.f;
      #pragma unroll
      for (int kt = 0; kt < 4; ++kt)
        #pragma unroll
        for (int r = 0; r < 4; ++r) {
          float p = exp2f(sc[kt][r] - mrun);
          sc[kt][r] = p;
          s += p;
        }
      s += __shfl_xor(s, 16);
      s += __shfl_xor(s, 32);
      lrun += s;

      // ---- PV A-fragments: pure in-lane pack (sigma made slots line up) ----
      union { unsigned int u[4]; bf16x8 v8; } pa[2];
      #pragma unroll
      for (int ks = 0; ks < 2; ++ks) {
        pa[ks].u[0] = pk2bf(sc[2 * ks][0], sc[2 * ks][1]);
        pa[ks].u[1] = pk2bf(sc[2 * ks][2], sc[2 * ks][3]);
        pa[ks].u[2] = pk2bf(sc[2 * ks + 1][0], sc[2 * ks + 1][1]);
        pa[ks].u[3] = pk2bf(sc[2 * ks + 1][2], sc[2 * ks + 1][3]);
      }

      // ---- PV ----
      #pragma unroll
      for (int dt = 0; dt < 4; ++dt)
        #pragma unroll
        for (int ks = 0; ks < 2; ++ks) {
          int row = dt * 16 + lr;
          bf16x8 vb = *(const bf16x8*)(smV[cur] + row * 128 +
                                       (((ks * 64) + 16 * lg) ^ ((row & 7) << 4)));
          acc_o[dt] = __builtin_amdgcn_mfma_f32_16x16x32_bf16(pa[ks].v8, vb, acc_o[dt], 0, 0, 0);
        }
    }

    if (t < 256 && kti + 1 < ntiles) write_lds(cur ^ 1);  // buf cur^1 free since barrier
    __syncthreads();
  }

  // ---- normalize and write out (bf16) ----
  const float inv = 1.0f / lrun;   // for q-row qw0+lr
  float invO[4];
  #pragma unroll
  for (int r = 0; r < 4; ++r)
    invO[r] = __shfl(inv, (l & 48) | (lg * 4 + r));
  #pragma unroll
  for (int dt = 0; dt < 4; ++dt)
    #pragma unroll
    for (int r = 0; r < 4; ++r)
      attn_out[(size_t)(b * S_ + qw0 + lg * 4 + r) * D_ + h * DH_ + dt * 16 + lr] =
          f2bf(acc_o[dt][r] * invO[r]);
}

extern "C" void kernel_launch(void* const* d_in, const int* in_sizes, int n_in,
                              void* d_out, int out_size, void* d_ws, size_t ws_size,
                              hipStream_t stream) {
  const float* x     = (const float*)d_in[0];
  const float* W_qkv = (const float*)d_in[1];
  const float* b_qkv = (const float*)d_in[2];
  const float* W_out = (const float*)d_in[3];
  const float* b_out = (const float*)d_in[4];
  float* out = (float*)d_out;

  char* ws = (char*)d_ws;
  unsigned short* qkv_bf  = (unsigned short*)ws;  ws += (size_t)M_ * QKV_LD * 2;
  unsigned short* attn_bf = (unsigned short*)ws;  ws += (size_t)M_ * D_ * 2;
  unsigned short* x_bf    = (unsigned short*)ws;  ws += (size_t)M_ * D_ * 2;
  unsigned short* wqkvT   = (unsigned short*)ws;  ws += (size_t)QKV_LD * D_ * 2;
  unsigned short* woutT   = (unsigned short*)ws;

  dim3 blk(256);
  // fused prep: conv (4096 blocks) + W_qkv^T (3072) + W_out^T (1024)
  prep_all<<<4096 + 3072 + 1024, blk, 0, stream>>>(x, x_bf, W_qkv, wqkvT, W_out, woutT);
  gemm_bf16_tn<unsigned short><<<dim3(QKV_LD / 128, M_ / 128), blk, 0, stream>>>(
      x_bf, wqkvT, b_qkv, qkv_bf, QKV_LD, D_);
  // lo/hi wave-split balanced pairing + XCD-pinned bh (remap inside kernel)
  attn_fwd_mfma<<<dim3(512), dim3(512), 0, stream>>>(qkv_bf, attn_bf);
  gemm_bf16_tn<float><<<dim3(D_ / 128, M_ / 128), blk, 0, stream>>>(
      attn_bf, woutT, b_out, out, D_, D_);
}